// Round 12
// baseline (5644.904 us; speedup 1.0000x reference)
//
#include <hip/hip_runtime.h>
#include <hip/hip_bf16.h>
#include <math.h>

// ---------------- problem constants ----------------
#define NN     4096
#define INLEN  564
#define NT     24
#define NC1    32
#define NC2    64
#define KS     10
#define EPS    1e-5f

typedef short s8v __attribute__((ext_vector_type(8)));
typedef short s4v __attribute__((ext_vector_type(4)));
typedef float f4v __attribute__((ext_vector_type(4)));
typedef float f2v __attribute__((ext_vector_type(2)));

// raw barrier: waits LDS ops only, leaves vmcnt outstanding so global
// prefetch survives the barrier (T4). sched_barrier(0) pins movement.
#define LBAR() do { asm volatile("s_waitcnt lgkmcnt(0)" ::: "memory"); \
                    __builtin_amdgcn_sched_barrier(0); \
                    __builtin_amdgcn_s_barrier(); \
                    __builtin_amdgcn_sched_barrier(0); } while(0)

// ---------------- workspace layout (float offsets) ----------------
static const long O_COLS   = 0;          // 8960
static const long O_COLSQ  = 8960;       // 8960
static const long O_STATS  = 17920;      // 24*128
static const long O_H      = 20992;      // 4096*64 -> 283136
static const long ZERO_FLOATS = 291328;
static const long O_A1     = 291328;     // 768
static const long O_D1     = 292096;     // 768
static const long O_CB2    = 292864;     // 1536 -> ends 294400
// ---- embedding phase ----
static const long O_W2B    = 532480;     // bf16 245,760 float slots, ends 778,240
static const long O_G1P    = 778240;     // bf16 4096*280*32 -> ends 19,128,320
static const long O_Y2     = 19128320;   // bf16 4096*64*68 -> ends 28,041,216
static const long O_EMBS   = 28041216;   // fp32 24*4096*64 -> ends 34,332,672
// ---- encoder/decoder overlay (w2b/g1p/y2 dead) ----
static const long O_ADJB   = 532480;     // bf16 4096^2 -> ends 8,921,088
static const long O_PP     = 8921088;    // fp32 partials (enc z=8 N=128 / z=16 N=64; ends 13,115,392)
static const long O_X      = 13115392;   // decoder P2B only
static const long O_T1     = 13901824;   // 524288
static const long O_T1T    = 14426112;   // 262144
static const long O_T2     = 14688256;   // 524288
static const long O_RH     = 15212544;   // 262144
static const long O_RHT    = 15474688;   // 131072 (bf16 64x4096)
static const long O_P1S    = 15605760;   // 262144
static const long O_P1ST   = 15867904;   // 131072
static const long O_P2S    = 15998976;   // 262144
static const long O_UE     = 16261120;   // 131072 (bf16 4096*64) -> ends 16,392,192
// ---- encoder per-t X buffers (live ONLY during encoder; decoder overlays) ----
static const long O_X12    = 16392192;   // fp32 12*4096*128 -> ends 22,683,648
static const long O_XT12   = 22683648;   // bf16 12*128*4096 -> ends 25,829,376
// ---- decoder (X12/XT12 dead by then) ----
static const long O_EB     = 16392192;   // fp32 4096*896 = 3,670,016
static const long O_EBT    = 20062208;   // bf16 896*4096 -> 1,835,008 (reused: RHbt ONLY)
static const long O_AE1    = 21897216;   // 3,670,016
static const long O_AE1T   = 25567232;   // 1,835,008 (reused: ud bf16)
static const long O_AE2    = 27795456;   // 3,670,016 (overlays embs AFTER gatherE consumed it)
static const long O_RHB    = 31465472;   // 3,145,728
static const long O_P1B    = 34611200;   // 3,145,728 -> peak 151.0 MB
static const long O_P1BT   = O_PP;       // bf16 768x4096 -> 1,572,864 slots
static const long O_P2B    = O_X;        // 3,145,728
static const long O_HD     = O_PP;       // written only by final ggemm (P1Bt dead)

struct Src { const float* p; int ld; int off; int tmul; };

static __device__ __forceinline__ float cvt_bf(short s) {
  return __uint_as_float(((unsigned)(unsigned short)s) << 16);
}
static __device__ __forceinline__ short bf16bits(float v) {
  __hip_bfloat16_raw r = __hip_bfloat16_raw(__float2bfloat16(v));
  return (short)r.x;
}

// ---------------- conv1 ----------------
__global__ __launch_bounds__(256) void k_conv1n(const float* __restrict__ inp,
    const float* __restrict__ w1, const float* __restrict__ b1,
    __hip_bfloat16* __restrict__ g1p) {
  __shared__ float xin[INLEN];
  __shared__ float wl[320];
  __shared__ float bl[32];
  int n = blockIdx.x, tid = threadIdx.x;
  for (int i=tid; i<INLEN; i+=256) xin[i] = inp[(long)n*INLEN + i];
  for (int i=tid; i<320; i+=256) wl[i] = w1[i];
  if (tid < 32)  bl[tid] = b1[tid];
  __syncthreads();
  int c = tid & 31, pb = tid >> 5;
  float wreg[KS];
  #pragma unroll
  for (int k=0;k<KS;k++) wreg[k] = wl[c*KS+k];
  float bias = bl[c];
  for (int p = pb; p < 280; p += 8) {
    float acc = 0.f;
    if (p < 278) {
      acc = bias;
      #pragma unroll
      for (int k=0;k<KS;k++) acc = fmaf(wreg[k], xin[2*p+k], acc);
      acc = fmaxf(acc, 0.f);
    }
    g1p[((long)n*280 + p)*32 + c] = __float2bfloat16(acc);
  }
}

// ---------------- BN1 column sums ----------------
__global__ __launch_bounds__(256) void k_colsum2(const __hip_bfloat16* __restrict__ g1p,
    float* __restrict__ colS, float* __restrict__ colSQ) {
  int gid = blockIdx.x*256 + threadIdx.x;
  int cg = gid % 1120, chunk = gid / 1120;
  int col0 = cg*8;
  float s[8], sq[8];
  #pragma unroll
  for (int j=0;j<8;j++) { s[j]=0.f; sq[j]=0.f; }
  int n0 = chunk*128;
  const short* gp = (const short*)g1p;
  for (int n=n0; n<n0+128; n++) {
    s8v v = *(const s8v*)(gp + (long)n*8960 + col0);
    #pragma unroll
    for (int j=0;j<8;j++) { float f = cvt_bf(v[j]); s[j]+=f; sq[j]+=f*f; }
  }
  #pragma unroll
  for (int j=0;j<8;j++) { atomicAdd(&colS[col0+j], s[j]); atomicAdd(&colSQ[col0+j], sq[j]); }
}

__global__ __launch_bounds__(64) void k_bn1aff(const float* __restrict__ colS,
    const float* __restrict__ colSQ, const float* __restrict__ g, const float* __restrict__ b,
    float* __restrict__ a1, float* __restrict__ d1) {
  int i = blockIdx.x*64 + threadIdx.x;
  if (i >= NT*NC1) return;
  int t = i / NC1, c = i % NC1;
  float s=0.f, sq=0.f;
  for (int p=6*t; p<6*t+140; p++) { s += colS[p*32+c]; sq += colSQ[p*32+c]; }
  float cnt = 4096.f*140.f;
  float m = s/cnt;
  float v = sq/cnt - m*m;
  float a = g[c]*rsqrtf(v+EPS);
  a1[i] = a;
  d1[i] = b[c] - m*a;
}

// ---------------- fold BN1 into conv2 weights ----------------
__global__ __launch_bounds__(256) void k_w2b(const float* __restrict__ w2,
    const float* __restrict__ b2, const float* __restrict__ a1, const float* __restrict__ d1,
    __hip_bfloat16* __restrict__ w2b, float* __restrict__ cb2) {
  int i = blockIdx.x*256 + threadIdx.x;
  if (i >= NT*NC2) return;
  int t = i>>6, c2 = i&63;
  float cb = b2[c2];
  for (int c1=0;c1<NC1;c1++) {
    float a = a1[t*32+c1], d = d1[t*32+c1];
    float wsum = 0.f;
    for (int k=0;k<KS;k++) {
      float wv = w2[(c2*32+c1)*KS+k];
      wsum += wv;
      w2b[(((long)t*10 + k)*64 + c2)*32 + c1] = __float2bfloat16(wv*a);
    }
    cb += wsum*d;
  }
  cb2[i] = cb;
}

// ---------------- conv2 as 10 accumulated MFMAs ------
__global__ __launch_bounds__(256) void k_conv2m(const __hip_bfloat16* __restrict__ g1p,
    const __hip_bfloat16* __restrict__ w2b, const float* __restrict__ cb2,
    __hip_bfloat16* __restrict__ y2, float* __restrict__ stats, int t) {
  __shared__ __attribute__((aligned(16))) short patch[4*140*40];
  __shared__ float sS[64], sQ[64];
  int tid = threadIdx.x, w = tid>>6, lane = tid&63;
  int n0 = blockIdx.x*4;
  if (tid < 64) { sS[tid]=0.f; sQ[tid]=0.f; }
  const short* gp = (const short*)g1p;
  for (int f = tid; f < 2240; f += 256) {
    int nn = f / 560, rr = f % 560;
    int row = rr >> 2, kq = rr & 3;
    s8v v = *(const s8v*)(gp + ((long)(n0+nn)*280 + 6*t + row)*32 + kq*8);
    *(s8v*)&patch[(nn*140 + row)*40 + kq*8] = v;
  }
  __syncthreads();
  int q = lane>>4, m = lane&15;
  f4v acc[5][4];
  #pragma unroll
  for (int a=0;a<5;a++)
    #pragma unroll
    for (int b=0;b<4;b++) acc[a][b] = (f4v){0.f,0.f,0.f,0.f};
  const short* wb = (const short*)w2b + (long)t*10*64*32;
  for (int s=0; s<10; s++) {
    int j = s>>1, r = s&1;
    s8v bfr[4];
    #pragma unroll
    for (int ng=0; ng<4; ng++)
      bfr[ng] = *(const s8v*)(wb + (long)(s*64 + ng*16 + m)*32 + q*8);
    #pragma unroll
    for (int mg=0; mg<5; mg++) {
      int l2 = mg*16 + m;
      int u = l2 + j; u = (u>69)?69:u;
      s8v afr = *(const s8v*)&patch[(w*140 + 2*u + r)*40 + q*8];
      #pragma unroll
      for (int ng=0; ng<4; ng++)
        acc[mg][ng] = __builtin_amdgcn_mfma_f32_16x16x32_bf16(afr, bfr[ng], acc[mg][ng], 0,0,0);
    }
  }
  int node = n0 + w;
  float s1a[4]={0,0,0,0}, s2a[4]={0,0,0,0};
  #pragma unroll
  for (int mg=0; mg<5; mg++) {
    int l2b = mg*16 + q*4;
    #pragma unroll
    for (int ng=0; ng<4; ng++) {
      int c2 = ng*16 + m;
      float cbv = cb2[t*64 + c2];
      float vv[4];
      #pragma unroll
      for (int rr=0; rr<4; rr++) {
        float v = fmaxf(acc[mg][ng][rr] + cbv, 0.f);
        vv[rr] = v;
        if (l2b + rr < 66) { s1a[ng] += v; s2a[ng] += v*v; }
      }
      long base = ((long)node*64 + c2)*68 + l2b;
      if (mg < 4) {
        s4v o;
        #pragma unroll
        for (int rr=0; rr<4; rr++) o[rr] = bf16bits(vv[rr]);
        *(s4v*)((short*)y2 + base) = o;
      } else {
        for (int rr=0; rr<4; rr++) if (l2b+rr < 66) y2[base+rr] = __float2bfloat16(vv[rr]);
      }
    }
  }
  #pragma unroll
  for (int ng=0; ng<4; ng++) {
    atomicAdd(&sS[ng*16+m], s1a[ng]);
    atomicAdd(&sQ[ng*16+m], s2a[ng]);
  }
  __syncthreads();
  if (tid < 64) {
    atomicAdd(&stats[t*128+tid], sS[tid]);
    atomicAdd(&stats[t*128+64+tid], sQ[tid]);
  }
}

// ---------------- BN2 + fcconv + relu + fc ----------------
__global__ __launch_bounds__(256) void k_pass2(const __hip_bfloat16* __restrict__ y2,
    const float* __restrict__ stats, const float* __restrict__ bn2g, const float* __restrict__ bn2b,
    const float* __restrict__ fcvw, const float* __restrict__ fcvb,
    const float* __restrict__ fcW, const float* __restrict__ fcB,
    float* __restrict__ embs, int t) {
  __shared__ __attribute__((aligned(16))) short yb[4*64*68];
  __shared__ float fw[66*64];
  __shared__ float fwa[64], cfcs[64];
  __shared__ float zbuf[4][68];
  int tid = threadIdx.x;
  int n0 = blockIdx.x*4;
  const short* yg = (const short*)y2;
  for (int f=tid; f<2176; f+=256)
    *(s8v*)&yb[f*8] = *(const s8v*)(yg + (long)n0*64*68 + f*8);
  for (int i=tid; i<66*64; i+=256) fw[i] = fcW[i];
  if (tid < 64) {
    float cnt = 4096.f*66.f;
    float m = stats[t*128+tid]/cnt;
    float v = stats[t*128+64+tid]/cnt - m*m;
    float a = bn2g[tid]*rsqrtf(v+EPS);
    float d = bn2b[tid] - m*a;
    fwa[tid]  = fcvw[tid]*a;
    cfcs[tid] = fcvw[tid]*d;
  }
  __syncthreads();
  float cfc = fcvb[0];
  #pragma unroll 8
  for (int c=0;c<64;c++) cfc += cfcs[c];
  for (int idx=tid; idx<4*66; idx+=256) {
    int nn = idx/66, l = idx%66;
    float z = cfc;
    #pragma unroll 8
    for (int c=0;c<64;c++) z = fmaf(fwa[c], cvt_bf(yb[(nn*64+c)*68 + l]), z);
    zbuf[nn][l] = fmaxf(z, 0.f);
  }
  __syncthreads();
  int nn = tid>>6, e = tid&63;
  float acc = fcB[e];
  for (int l=0;l<66;l++) acc = fmaf(zbuf[nn][l], fw[l*64+e], acc);
  embs[((long)t*NN + n0+nn)*64 + e] = acc;
}

// ---------------- adj fp32 -> bf16 ----------------
__global__ __launch_bounds__(256) void k_cvtadj(const float* __restrict__ adj,
    __hip_bfloat16* __restrict__ adjb) {
  long gid = ((long)blockIdx.x*256 + threadIdx.x)*4;
  float4 v = *(const float4*)(adj + gid);
  adjb[gid+0] = __float2bfloat16(v.x);
  adjb[gid+1] = __float2bfloat16(v.y);
  adjb[gid+2] = __float2bfloat16(v.z);
  adjb[gid+3] = __float2bfloat16(v.w);
}

// ---------------- bf16 MFMA GEMM: P = A @ Bt^T ----------
// BM=64, 2-deep register prefetch, LBAR barriers (vmcnt stays outstanding).
// zsplit>1: store partials only; k_redT reduces (kernel-boundary sync).
// zsplit==1: direct fused epilogue (mode, fp32 dst, optional bf16T) from acc.
template<int BN>
__global__ __launch_bounds__(256) void k_mmb(const __hip_bfloat16* __restrict__ A,
    const __hip_bfloat16* __restrict__ Bt, float* __restrict__ P,
    int N, int kchunk, long zoff,
    float* __restrict__ dst, const float* __restrict__ ref,
    __hip_bfloat16* __restrict__ dstT, int mode, int writeT, int zsplit) {
  constexpr int BM = 64;
  constexpr int WN = BN/2;
  constexpr int MI = 2;
  constexpr int NJ = WN/16;
  constexpr int AIT = 2;
  constexpr int BIT = BN*8/256;
  __shared__ __attribute__((aligned(16))) short As[BM*64];
  __shared__ __attribute__((aligned(16))) short Bs[BN*64];
  int tid = threadIdx.x;
  int w = tid >> 6, lane = tid & 63;
  int wm = w >> 1, wn = w & 1;
  int q = lane >> 4, m = lane & 15;
  long Mb = (long)blockIdx.x * BM;
  int Nb = blockIdx.y * BN;
  int k0 = blockIdx.z * kchunk;
  const short* Ag = (const short*)A;
  const short* Bg = (const short*)Bt;
  s8v arA[AIT], brA[BIT], arB[AIT], brB[BIT];

  auto loadAr = [&](s8v* d, int kb){
    #pragma unroll
    for (int i2=0;i2<AIT;i2++){ int f=tid+i2*256; int kq=f&7, row=f>>3;
      d[i2] = *(const s8v*)(Ag + (Mb+row)*4096 + kb + kq*8); } };
  auto loadBr = [&](s8v* d, int kb){
    #pragma unroll
    for (int i2=0;i2<BIT;i2++){ int f=tid+i2*256; int kq=f&7, col=f>>3;
      d[i2] = *(const s8v*)(Bg + (long)(Nb+col)*4096 + kb + kq*8); } };

  f4v acc[MI][NJ];
  #pragma unroll
  for (int i=0;i<MI;i++)
    #pragma unroll
    for (int j=0;j<NJ;j++) acc[i][j] = (f4v){0.f,0.f,0.f,0.f};

  auto writeS = [&](s8v* a, s8v* b){
    #pragma unroll
    for (int i2=0;i2<AIT;i2++){ int f=tid+i2*256; int kq=f&7, row=f>>3;
      *(s8v*)&As[(row*8 + (kq ^ (row&7)))*8] = a[i2]; }
    #pragma unroll
    for (int i2=0;i2<BIT;i2++){ int f=tid+i2*256; int kq=f&7, col=f>>3;
      *(s8v*)&Bs[(col*8 + (kq ^ (col&7)))*8] = b[i2]; } };
  auto compute = [&](){
    #pragma unroll
    for (int h2=0; h2<2; ++h2) {
      s8v af[MI], bfv[NJ];
      #pragma unroll
      for (int i=0;i<MI;i++) {
        int row = wm*32 + i*16 + m;
        af[i] = *(const s8v*)&As[(row*8 + ((h2*4+q) ^ (row&7)))*8];
      }
      #pragma unroll
      for (int j=0;j<NJ;j++) {
        int col = wn*WN + j*16 + m;
        bfv[j] = *(const s8v*)&Bs[(col*8 + ((h2*4+q) ^ (col&7)))*8];
      }
      #pragma unroll
      for (int i=0;i<MI;i++)
        #pragma unroll
        for (int j=0;j<NJ;j++)
          acc[i][j] = __builtin_amdgcn_mfma_f32_16x16x32_bf16(af[i], bfv[j], acc[i][j], 0, 0, 0);
    } };

  loadAr(arA, k0);      loadBr(brA, k0);
  loadAr(arB, k0+64);   loadBr(brB, k0+64);
  int kiters = kchunk >> 6;   // always even here (4, 8 or 64)
  for (int it = 0; it < kiters; it += 2) {
    LBAR();                  // all waves' LDS reads of prev tile done
    writeS(arA, brA);        // vmcnt auto-wait only on arA/brA deps
    LBAR();                  // ds_writes visible
    { int kn = (it+2 < kiters) ? k0 + (it+2)*64 : k0;
      loadAr(arA, kn); loadBr(brA, kn); }   // stays in flight across barriers
    compute();
    LBAR();
    writeS(arB, brB);
    LBAR();
    { int kn = (it+3 < kiters) ? k0 + (it+3)*64 : k0;
      loadAr(arB, kn); loadBr(brB, kn); }
    compute();
  }

  if (zsplit > 1) {
    float* pp = P + (long)blockIdx.z * zoff;
    #pragma unroll
    for (int i=0;i<MI;i++) {
      long row0 = Mb + wm*32 + i*16 + q*4;
      #pragma unroll
      for (int j=0;j<NJ;j++) {
        int col = Nb + wn*WN + j*16 + m;
        #pragma unroll
        for (int r=0;r<4;r++) pp[(row0+r)*N + col] = acc[i][j][r];
      }
    }
  } else {
    #pragma unroll
    for (int i=0;i<MI;i++) {
      long row0 = Mb + wm*32 + i*16 + q*4;
      #pragma unroll
      for (int j=0;j<NJ;j++) {
        int col = Nb + wn*WN + j*16 + m;
        float vr[4];
        #pragma unroll
        for (int r=0;r<4;r++) {
          long idx = (row0+r)*N + col;
          float v = acc[i][j][r];
          if (mode) v = 2.f*v - ref[idx];
          dst[idx] = v;
          vr[r] = v;
        }
        if (writeT) {
          s4v o;
          #pragma unroll
          for (int r=0;r<4;r++) o[r] = bf16bits(vr[r]);
          *(s4v*)((short*)dstT + (long)col*4096 + row0) = o;
        }
      }
    }
  }
}

// ---------------- split-K reduce + optional (2x-ref) + optional bf16T -------
__global__ __launch_bounds__(256) void k_redT(const float* __restrict__ P,
    float* __restrict__ dst, const float* __restrict__ ref,
    __hip_bfloat16* __restrict__ dstT, int ldc, int ksplit, long zoff, int mode,
    int writeF, int writeT) {
  __shared__ float tile[64][65];
  int tid = threadIdx.x;
  int n0 = blockIdx.x*64, c0 = blockIdx.y*64;
  for (int i=0; i<16; i++) {
    int flat = i*256 + tid;
    int cc = flat & 63, nn = flat >> 6;
    long idx = (long)(n0+nn)*ldc + c0+cc;
    float v = P[idx];
    for (int s=1; s<ksplit; s++) v += P[(long)s*zoff + idx];
    if (mode) v = 2.f*v - ref[idx];
    if (writeF) dst[idx] = v;
    tile[nn][cc] = v;
  }
  __syncthreads();
  if (writeT) {
    for (int i=0; i<16; i++) {
      int flat = i*256 + tid;
      int nn = flat & 63, cc = flat >> 6;
      dstT[(long)(c0+cc)*4096 + n0+nn] = __float2bfloat16(tile[nn][cc]);
    }
  }
}

// ---------------- prepX: all 12 X=[et|0] fp32 + Xt bf16 in one launch ------
__global__ __launch_bounds__(256) void k_prepX(const float* __restrict__ embs,
    float* __restrict__ X12, __hip_bfloat16* __restrict__ Xt12) {
  __shared__ float tile[64][65];
  int tid = threadIdx.x;
  int n0 = blockIdx.x*64, c0 = blockIdx.y*64, t = blockIdx.z;
  float* X = X12 + (long)t*524288;
  __hip_bfloat16* Xt = Xt12 + (long)t*524288;
  for (int i=0; i<16; i++) {
    int flat = i*256 + tid;
    int cc = flat & 63, nn = flat >> 6;
    int col = c0 + cc, n = n0 + nn;
    float v = (col < 64) ? embs[((long)t*NN + n)*64 + col] : 0.f;
    X[(long)n*128 + col] = v;
    tile[nn][cc] = v;
  }
  __syncthreads();
  for (int i=0; i<16; i++) {
    int flat = i*256 + tid;
    int nn = flat & 63, cc = flat >> 6;
    Xt[(long)(c0+cc)*4096 + n0+nn] = __float2bfloat16(tile[nn][cc]);
  }
}

// ---------------- Eb = [emb12..23 | h | 0pad] fp32 ld896 + Ebt bf16 ---------
__global__ __launch_bounds__(256) void k_gatherE(const float* __restrict__ embs,
    const float* __restrict__ h, float* __restrict__ Eb, __hip_bfloat16* __restrict__ Ebt) {
  __shared__ float tile[64][65];
  int tid = threadIdx.x;
  int n0 = blockIdx.x*64, c0 = blockIdx.y*64;
  for (int i=0; i<16; i++) {
    int flat = i*256 + tid;
    int cc = flat & 63, nn = flat >> 6;
    int col = c0 + cc, n = n0 + nn;
    float v;
    if (col < 768)      v = embs[((long)(12 + (col>>6))*NN + n)*64 + (col & 63)];
    else if (col < 832) v = h[(long)n*64 + (col - 768)];
    else                v = 0.f;
    Eb[(long)n*896 + col] = v;
    tile[nn][cc] = v;
  }
  __syncthreads();
  for (int i=0; i<16; i++) {
    int flat = i*256 + tid;
    int nn = flat & 63, cc = flat >> 6;
    Ebt[(long)(c0+cc)*4096 + n0+nn] = __float2bfloat16(tile[nn][cc]);
  }
}

// ---------------- gather-GEMM + fused DCGRU epilogue (fp32 FMA, encoder) ----
template<int RPT>
__global__ __launch_bounds__(256) void k_ggemm2(
    Src s0, Src s1, Src s2, Src s3, Src s4, Src s5,
    const float* __restrict__ W, const float* __restrict__ bias, int N, int mode,
    float* __restrict__ o1, int ld1, int t1, __hip_bfloat16* __restrict__ o1t,
    __hip_bfloat16* __restrict__ o2, const float* __restrict__ h,
    float* __restrict__ xnext, __hip_bfloat16* __restrict__ xtnext) {
  constexpr int BM = 16*RPT;
  __shared__ float Ags[32][BM+4];
  __shared__ float Bgs[32][68];
  int tid = threadIdx.x;
  long Mb = (long)blockIdx.x * BM;
  int Nb = blockIdx.y * 64;
  int tr = tid >> 4, tc = tid & 15;
  float acc[RPT][4];
  #pragma unroll
  for (int a=0;a<RPT;a++)
    #pragma unroll
    for (int b=0;b<4;b++) acc[a][b] = 0.f;
  float ar[2*RPT], br[8];
  auto pick = [&](int c)->Src {
    switch (c >> 1) {
      case 0: return s0; case 1: return s1; case 2: return s2;
      case 3: return s3; case 4: return s4; default: return s5;
    } };
  auto loadA = [&](int c){
    Src S = pick(c); int cc0 = (c & 1)*32;
    #pragma unroll
    for (int h0=0; h0<2*RPT; h0++) {
      int idx = tid + h0*256;
      int kk = idx & 31, mm = idx >> 5;
      long row = Mb + mm; int tt = (int)(row >> 12); int n = (int)(row & 4095);
      ar[h0] = S.p[(long)n*S.ld + S.off + S.tmul*(tt*64) + cc0 + kk];
    } };
  auto loadB = [&](int c){
    #pragma unroll
    for (int h0=0; h0<8; h0++) {
      int idx = tid + h0*256;
      int kk = idx >> 6, cc = idx & 63;
      br[h0] = W[(long)(c*32+kk)*N + Nb + cc];
    } };
  loadA(0); loadB(0);
  for (int c=0; c<12; c++) {
    LBAR();
    #pragma unroll
    for (int h0=0; h0<2*RPT; h0++) {
      int idx = tid + h0*256;
      int kk = idx & 31, mm = idx >> 5;
      Ags[kk][mm] = ar[h0];
    }
    #pragma unroll
    for (int h0=0; h0<8; h0++)     { int idx = tid + h0*256; Bgs[idx >> 6][idx & 63] = br[h0]; }
    LBAR();
    if (c < 11) { loadA(c+1); loadB(c+1); }
    #pragma unroll
    for (int kk=0; kk<32; kk++) {
      f4v b4 = *(const f4v*)&Bgs[kk][tc*4];
      if constexpr (RPT == 2) {
        f2v a0 = *(const f2v*)&Ags[kk][tr*2];
        #pragma unroll
        for (int rr=0; rr<2; rr++)
          #pragma unroll
          for (int j=0; j<4; j++)
            acc[rr][j] = fmaf(a0[rr], b4[j], acc[rr][j]);
      } else {
        float a0 = Ags[kk][tr];
        #pragma unroll
        for (int j=0; j<4; j++)
          acc[0][j] = fmaf(a0, b4[j], acc[0][j]);
      }
    }
  }
  #pragma unroll
  for (int rr=0; rr<RPT; rr++) {
    long row = Mb + tr*RPT + rr;
    int tt = (int)(row >> 12); int n = (int)(row & 4095);
    #pragma unroll
    for (int j=0; j<4; j++) {
      int col = Nb + tc*4 + j;
      float g = acc[rr][j] + bias[col];
      if (mode == 0) {
        float sg = 1.f/(1.f + expf(-g));
        if (col < 64) {
          float v = sg * h[(long)n*64 + col];
          o1[(long)n*ld1 + (long)t1*tt*64 + col] = v;
          o1t[((long)t1*tt*64 + col)*4096 + n] = __float2bfloat16(v);
        } else {
          o2[(long)row*64 + (col - 64)] = __float2bfloat16(sg);
        }
      } else {
        float uu = __bfloat162float(o2[(long)row*64 + col]);
        float v = uu*h[(long)n*64 + col] + (1.f - uu)*tanhf(g);
        o1[(long)row*64 + col] = v;
        if (xnext) {
          xnext[(long)n*128 + 64 + col] = v;
          xtnext[(long)(64 + col)*4096 + n] = __float2bfloat16(v);
        }
      }
    }
  }
}

// ---------------- MFMA gather-GEMM + fused DCGRU epilogue (decoder) ----
__global__ __launch_bounds__(256) void k_ggemm3(
    Src s0, Src s1, Src s2, Src s3, Src s4, Src s5,
    const float* __restrict__ W, const float* __restrict__ bias, int N, int mode,
    float* __restrict__ o1, int ld1, int t1, __hip_bfloat16* __restrict__ o1t,
    __hip_bfloat16* __restrict__ o2, const float* __restrict__ h) {
  __shared__ __attribute__((aligned(16))) short As[64*32];
  __shared__ __attribute__((aligned(16))) short Bs[64*32];
  int tid = threadIdx.x;
  int w = tid >> 6, lane = tid & 63;
  int wm = w >> 1, wn = w & 1;
  int q = lane >> 4, m = lane & 15;
  long Mb = (long)blockIdx.x * 64;
  int Nb = blockIdx.y * 64;
  int arow = tid >> 2, ag = tid & 3;
  int bnn  = tid & 63, bg = tid >> 6;
  auto pick = [&](int c)->Src {
    switch (c >> 1) {
      case 0: return s0; case 1: return s1; case 2: return s2;
      case 3: return s3; case 4: return s4; default: return s5;
    } };
  f4v a0r, a1r; float wr[8];
  auto loadA = [&](int c){
    Src S = pick(c); int cc0 = (c & 1)*32;
    long row = Mb + arow; int tt = (int)(row >> 12); int n = (int)(row & 4095);
    const float* p = S.p + (long)n*S.ld + S.off + S.tmul*(tt*64) + cc0 + ag*8;
    a0r = *(const f4v*)p; a1r = *(const f4v*)(p+4);
  };
  auto loadB = [&](int c){
    #pragma unroll
    for (int jj=0;jj<8;jj++) wr[jj] = W[(long)(c*32 + bg*8 + jj)*N + Nb + bnn];
  };
  f4v acc[2][2];
  #pragma unroll
  for (int i=0;i<2;i++)
    #pragma unroll
    for (int j=0;j<2;j++) acc[i][j] = (f4v){0.f,0.f,0.f,0.f};
  loadA(0); loadB(0);
  for (int c=0; c<12; c++) {
    LBAR();
    {
      s8v va;
      #pragma unroll
      for (int jj=0;jj<4;jj++) { va[jj] = bf16bits(a0r[jj]); va[4+jj] = bf16bits(a1r[jj]); }
      *(s8v*)&As[(arow*4 + (ag ^ (arow&3)))*8] = va;
      s8v vb;
      #pragma unroll
      for (int jj=0;jj<8;jj++) vb[jj] = bf16bits(wr[jj]);
      *(s8v*)&Bs[(bnn*4 + (bg ^ (bnn&3)))*8] = vb;
    }
    LBAR();
    if (c < 11) { loadA(c+1); loadB(c+1); }
    s8v af[2], bfv[2];
    #pragma unroll
    for (int i=0;i<2;i++) {
      int row = wm*32 + i*16 + m;
      af[i] = *(const s8v*)&As[(row*4 + (q ^ (row&3)))*8];
    }
    #pragma unroll
    for (int j=0;j<2;j++) {
      int col = wn*32 + j*16 + m;
      bfv[j] = *(const s8v*)&Bs[(col*4 + (q ^ (col&3)))*8];
    }
    #pragma unroll
    for (int i=0;i<2;i++)
      #pragma unroll
      for (int j=0;j<2;j++)
        acc[i][j] = __builtin_amdgcn_mfma_f32_16x16x32_bf16(af[i], bfv[j], acc[i][j], 0, 0, 0);
  }
  #pragma unroll
  for (int i=0;i<2;i++) {
    #pragma unroll
    for (int r=0;r<4;r++) {
      long row = Mb + wm*32 + i*16 + q*4 + r;
      int tt = (int)(row >> 12); int n = (int)(row & 4095);
      #pragma unroll
      for (int j=0;j<2;j++) {
        int col = Nb + wn*32 + j*16 + m;
        float g = acc[i][j][r] + bias[col];
        if (mode == 0) {
          float sg = 1.f/(1.f + expf(-g));
          if (col < 64) {
            float v = sg * h[(long)n*64 + col];
            o1[(long)n*ld1 + (long)t1*tt*64 + col] = v;
            o1t[((long)t1*tt*64 + col)*4096 + n] = __float2bfloat16(v);
          } else {
            o2[(long)row*64 + (col - 64)] = __float2bfloat16(sg);
          }
        } else {
          float uu = __bfloat162float(o2[(long)row*64 + col]);
          o1[(long)row*64 + col] = uu*h[(long)n*64 + col] + (1.f - uu)*tanhf(g);
        }
      }
    }
  }
}

// ---------------- preds ----------------
__global__ __launch_bounds__(256) void k_pred(const float* __restrict__ hd,
    const float* __restrict__ pw, const float* __restrict__ pb, float* __restrict__ out) {
  int gid = blockIdx.x*256 + threadIdx.x;
  int wid = gid >> 6;
  int lane = threadIdx.x & 63;
  if (wid >= 12*NN) return;
  int t = wid >> 12, n = wid & 4095;
  float hv = hd[(long)wid*64 + lane];
  float res = 0.f;
  #pragma unroll
  for (int p=0;p<12;p++) {
    float v = hv * pw[lane*12 + p];
    #pragma unroll
    for (int off=32; off>0; off>>=1) v += __shfl_xor(v, off, 64);
    if (lane == p) res = v + pb[p];
  }
  if (lane < 12) out[(long)n*144 + t*12 + lane] = res;
}

// ============================================================================
extern "C" void kernel_launch(void* const* d_in, const int* in_sizes, int n_in,
                              void* d_out, int out_size, void* d_ws, size_t ws_size,
                              hipStream_t stream) {
  const float* inp  = (const float*)d_in[0];
  const float* c1w  = (const float*)d_in[2];
  const float* c1b  = (const float*)d_in[3];
  const float* c2w  = (const float*)d_in[4];
  const float* c2b  = (const float*)d_in[5];
  const float* bn1g = (const float*)d_in[6];
  const float* bn1b = (const float*)d_in[7];
  const float* bn2g = (const float*)d_in[8];
  const float* bn2b = (const float*)d_in[9];
  const float* fcvw = (const float*)d_in[10];
  const float* fcvb = (const float*)d_in[11];
  const float* fcW  = (const float*)d_in[12];
  const float* fcB  = (const float*)d_in[13];
  const float* eWg  = (const float*)d_in[14];
  const float* ebg  = (const float*)d_in[15];
  const float* eWc  = (const float*)d_in[16];
  const float* ebc  = (const float*)d_in[17];
  const float* dWg  = (const float*)d_in[18];
  const float* dbg  = (const float*)d_in[19];
  const float* dWc  = (const float*)d_in[20];
  const float* dbc  = (const float*)d_in[21];
  const float* pw   = (const float*)d_in[22];
  const float* pb   = (const float*)d_in[23];
  const float* adj  = (const float*)d_in[n_in-1];
  for (int i=0;i<n_in;i++) if (in_sizes[i] == NN*NN) adj = (const float*)d_in[i];

  float* ws = (float*)d_ws;
  float* colS  = ws + O_COLS;
  float* colSQ = ws + O_COLSQ;
  float* stats = ws + O_STATS;
  float* h     = ws + O_H;
  float* a1    = ws + O_A1;
  float* d1    = ws + O_D1;
  float* cb2   = ws + O_CB2;
  __hip_bfloat16* w2b = (__hip_bfloat16*)(ws + O_W2B);
  __hip_bfloat16* g1p = (__hip_bfloat16*)(ws + O_G1P);
  __hip_bfloat16* y2  = (__hip_bfloat16*)(ws + O_Y2);
  float* embs  = ws + O_EMBS;
  __hip_bfloat16* adjb = (__hip_bfloat16*)(ws + O_ADJB);
  float* Pp    = ws + O_PP;
  float* T1    = ws + O_T1;
  __hip_bfloat16* T1t = (__hip_bfloat16*)(ws + O_T1T);
  float* T2    = ws + O_T2;
  float* rh    = ws + O_RH;
  __hip_bfloat16* rht = (__hip_bfloat16*)(ws + O_RHT);
  float* P1s   = ws + O_P1S;
  __hip_bfloat16* P1st = (__hip_bfloat16*)(ws + O_P1ST);
  float* P2s   = ws + O_P2S;
  __hip_bfloat16* ue  = (__hip_bfloat16*)(ws + O_UE);
  float* X12   = ws + O_X12;
  __hip_bfloat16* Xt12 = (__hip_bfloat16*)(ws + O_XT12);
  float* Eb    = ws + O_EB;
  __hip_bfloat16* Ebt = (__hip_bfloat16*)(ws + O_EBT);
  float* AE1   = ws + O_AE1;
  __hip_bfloat16* AE1t = (__hip_bfloat16*)(ws + O_AE1T);
  float* AE2   = ws + O_AE2;
  float* RHb   = ws + O_RHB;
  float* P1B   = ws + O_P1B;
  float* P2B   = ws + O_P2B;
  float* hd    = ws + O_HD;
  __hip_bfloat16* RHbt = Ebt;                              // Ebt dead by then
  __hip_bfloat16* P1Bt = (__hip_bfloat16*)(ws + O_P1BT);   // distinct from RHbt
  __hip_bfloat16* ud   = AE1t;

  auto S = [](const float* p, int ld, int off, int tmul){ Src s; s.p=p; s.ld=ld; s.off=off; s.tmul=tmul; return s; };

  hipMemsetAsync(ws, 0, ZERO_FLOATS*sizeof(float), stream);

  // ---- embedding (y2 path — measured faster than recompute variant) ----
  k_conv1n<<<4096, 256, 0, stream>>>(inp, c1w, c1b, g1p);
  k_colsum2<<<140, 256, 0, stream>>>(g1p, colS, colSQ);
  k_bn1aff<<<12, 64, 0, stream>>>(colS, colSQ, bn1g, bn1b, a1, d1);
  k_w2b   <<<6, 256, 0, stream>>>(c2w, c2b, a1, d1, w2b, cb2);
  for (int t=0; t<NT; t++) {
    k_conv2m<<<1024, 256, 0, stream>>>(g1p, w2b, cb2, y2, stats, t);
    k_pass2 <<<1024, 256, 0, stream>>>(y2, stats, bn2g, bn2b, fcvw, fcvb, fcW, fcB, embs, t);
  }

  // ---- adj -> bf16 (w2b/g1p dead now) ----
  k_cvtadj<<<16384, 256, 0, stream>>>(adj, adjb);

  // ---- encoder: BN=64 N-split (2x blocks) + deeper z on N=64 GEMMs ----
  k_prepX<<<dim3(64,2,12), 256, 0, stream>>>(embs, X12, Xt12);
  for (int t=0; t<12; t++) {
    const float* et = embs + (long)t*NN*64;
    float* X_t = X12 + (long)t*524288;
    __hip_bfloat16* Xt_t = Xt12 + (long)t*524288;
    float* Xn  = (t < 11) ? X12 + (long)(t+1)*524288 : (float*)nullptr;
    __hip_bfloat16* Xtn = (t < 11) ? Xt12 + (long)(t+1)*524288 : (__hip_bfloat16*)nullptr;
    k_mmb<64><<<dim3(64,2,8), 256, 0, stream>>>(adjb, Xt_t, Pp, 128, 512, 4096L*128,
        (float*)nullptr, (const float*)nullptr, (__hip_bfloat16*)nullptr, 0, 0, 8);
    k_redT<<<dim3(64,2), 256, 0, stream>>>(Pp, T1, (const float*)nullptr, T1t,
        128, 8, 4096L*128, 0, 1, 1);
    k_mmb<64><<<dim3(64,2,8), 256, 0, stream>>>(adjb, T1t, Pp, 128, 512, 4096L*128,
        (float*)nullptr, (const float*)nullptr, (__hip_bfloat16*)nullptr, 0, 0, 8);
    k_redT<<<dim3(64,2), 256, 0, stream>>>(Pp, T2, X_t, (__hip_bfloat16*)nullptr,
        128, 8, 4096L*128, 1, 1, 0);
    k_ggemm2<2><<<dim3(128,2), 256, 0, stream>>>(
        S(X_t,128,0,0), S(X_t,128,64,0), S(T1,128,0,0), S(T1,128,64,0), S(T2,128,0,0), S(T2,128,64,0),
        eWg, ebg, 128, 0, rh, 64, 0, rht, ue, h, (float*)nullptr, (__hip_bfloat16*)nullptr);
    k_mmb<64><<<dim3(64,1,16), 256, 0, stream>>>(adjb, rht, Pp, 64, 256, 4096L*64,
        (float*)nullptr, (const float*)nullptr, (__hip_bfloat16*)nullptr, 0, 0, 16);
    k_redT<<<dim3(64,1), 256, 0, stream>>>(Pp, P1s, (const float*)nullptr, P1st,
        64, 16, 4096L*64, 0, 1, 1);
    k_mmb<64><<<dim3(64,1,16), 256, 0, stream>>>(adjb, P1st, Pp, 64, 256, 4096L*64,
        (float*)nullptr, (const float*)nullptr, (__hip_bfloat16*)nullptr, 0, 0, 16);
    k_redT<<<dim3(64,1), 256, 0, stream>>>(Pp, P2s, rh, (__hip_bfloat16*)nullptr,
        64, 16, 4096L*64, 1, 1, 0);
    k_ggemm2<1><<<dim3(256,1), 256, 0, stream>>>(
        S(et,64,0,0), S(rh,64,0,0), S(T1,128,0,0), S(P1s,64,0,0), S(T2,128,0,0), S(P2s,64,0,0),
        eWc, ebc, 64, 1, h, 0, 0, (__hip_bfloat16*)nullptr, ue, h, Xn, Xtn);
  }

  // ---- decoder: BN=64 N-split z=1 mmb (2x blocks) + MFMA ggemm3 ----
  k_gatherE<<<dim3(64,14), 256, 0, stream>>>(embs, h, Eb, Ebt);
  k_mmb<64><<<dim3(64,14,1), 256, 0, stream>>>(adjb, Ebt, Pp, 896, 4096, 0,
      AE1, (const float*)nullptr, AE1t, 0, 1, 1);
  k_mmb<64><<<dim3(64,14,1), 256, 0, stream>>>(adjb, AE1t, Pp, 896, 4096, 0,
      AE2, Eb, (__hip_bfloat16*)nullptr, 1, 0, 1);
  k_ggemm3<<<dim3(768,2), 256, 0, stream>>>(
      S(Eb,896,0,1), S(Eb,896,768,0), S(AE1,896,0,1), S(AE1,896,768,0), S(AE2,896,0,1), S(AE2,896,768,0),
      dWg, dbg, 128, 0, RHb, 768, 1, RHbt, ud, h);
  k_mmb<64><<<dim3(64,12,1), 256, 0, stream>>>(adjb, RHbt, Pp, 768, 4096, 0,
      P1B, (const float*)nullptr, P1Bt, 0, 1, 1);
  k_mmb<64><<<dim3(64,12,1), 256, 0, stream>>>(adjb, P1Bt, Pp, 768, 4096, 0,
      P2B, RHb, (__hip_bfloat16*)nullptr, 1, 0, 1);
  k_ggemm3<<<dim3(768,1), 256, 0, stream>>>(
      S(Eb,896,0,1), S(RHb,768,0,1), S(AE1,896,0,1), S(P1B,768,0,1), S(AE2,896,0,1), S(P2B,768,0,1),
      dWc, dbc, 64, 1, hd, 0, 0, (__hip_bfloat16*)nullptr, ud, h);

  k_pred<<<12288, 256, 0, stream>>>(hd, pw, pb, (float*)d_out);
}

// Round 13
// 4885.021 us; speedup vs baseline: 1.1556x; 1.1556x over previous
//
#include <hip/hip_runtime.h>
#include <hip/hip_bf16.h>
#include <math.h>

// ---------------- problem constants ----------------
#define NN     4096
#define INLEN  564
#define NT     24
#define NC1    32
#define NC2    64
#define KS     10
#define EPS    1e-5f

typedef short s8v __attribute__((ext_vector_type(8)));
typedef short s4v __attribute__((ext_vector_type(4)));
typedef float f4v __attribute__((ext_vector_type(4)));
typedef float f2v __attribute__((ext_vector_type(2)));

// ---------------- workspace layout (float offsets) ----------------
static const long O_COLS   = 0;          // 8960
static const long O_COLSQ  = 8960;       // 8960
static const long O_STATS  = 17920;      // 24*128
static const long O_H      = 20992;      // 4096*64 -> 283136
static const long ZERO_FLOATS = 291328;
static const long O_A1     = 291328;     // 768
static const long O_D1     = 292096;     // 768
static const long O_CB2    = 292864;     // 1536 -> ends 294400
// ---- embedding phase ----
static const long O_W2B    = 532480;     // bf16 245,760 float slots, ends 778,240
static const long O_G1P    = 778240;     // bf16 4096*280*32 -> ends 19,128,320
static const long O_Y2     = 19128320;   // bf16 4096*64*68 -> ends 28,041,216
static const long O_EMBS   = 28041216;   // fp32 24*4096*64 -> ends 34,332,672
// ---- encoder/decoder overlay (w2b/g1p/y2 dead) ----
static const long O_ADJB   = 532480;     // bf16 4096^2 -> ends 8,921,088
static const long O_PP     = 8921088;    // fp32 partials (z=8; ends 13,115,392)
static const long O_X      = 13115392;   // decoder P2B only
static const long O_T1     = 13901824;   // 524288
static const long O_T1T    = 14426112;   // 262144
static const long O_T2     = 14688256;   // 524288
static const long O_RH     = 15212544;   // 262144
static const long O_RHT    = 15474688;   // 131072 (bf16 64x4096)
static const long O_P1S    = 15605760;   // 262144
static const long O_P1ST   = 15867904;   // 131072
static const long O_P2S    = 15998976;   // 262144
static const long O_UE     = 16261120;   // 131072 (bf16 4096*64) -> ends 16,392,192
// ---- encoder per-t X buffers (live ONLY during encoder; decoder overlays) ----
static const long O_X12    = 16392192;   // fp32 12*4096*128 -> ends 22,683,648
static const long O_XT12   = 22683648;   // bf16 12*128*4096 -> ends 25,829,376
// ---- decoder (X12/XT12 dead by then) ----
static const long O_EB     = 16392192;   // fp32 4096*896 = 3,670,016
static const long O_EBT    = 20062208;   // bf16 896*4096 -> 1,835,008 (reused: RHbt ONLY)
static const long O_AE1    = 21897216;   // 3,670,016
static const long O_AE1T   = 25567232;   // 1,835,008 (reused: ud bf16)
static const long O_AE2    = 27795456;   // 3,670,016 (overlays embs AFTER gatherE consumed it)
static const long O_RHB    = 31465472;   // 3,145,728
static const long O_P1B    = 34611200;   // 3,145,728 -> peak 151.0 MB
static const long O_P1BT   = O_PP;       // bf16 768x4096 -> 1,572,864 slots
static const long O_P2B    = O_X;        // 3,145,728
static const long O_HD     = O_PP;       // written only by final ggemm (P1Bt dead)

struct Src { const float* p; int ld; int off; int tmul; };

static __device__ __forceinline__ float cvt_bf(short s) {
  return __uint_as_float(((unsigned)(unsigned short)s) << 16);
}
static __device__ __forceinline__ short bf16bits(float v) {
  __hip_bfloat16_raw r = __hip_bfloat16_raw(__float2bfloat16(v));
  return (short)r.x;
}

// ---------------- conv1 ----------------
__global__ __launch_bounds__(256) void k_conv1n(const float* __restrict__ inp,
    const float* __restrict__ w1, const float* __restrict__ b1,
    __hip_bfloat16* __restrict__ g1p) {
  __shared__ float xin[INLEN];
  __shared__ float wl[320];
  __shared__ float bl[32];
  int n = blockIdx.x, tid = threadIdx.x;
  for (int i=tid; i<INLEN; i+=256) xin[i] = inp[(long)n*INLEN + i];
  for (int i=tid; i<320; i+=256) wl[i] = w1[i];
  if (tid < 32)  bl[tid] = b1[tid];
  __syncthreads();
  int c = tid & 31, pb = tid >> 5;
  float wreg[KS];
  #pragma unroll
  for (int k=0;k<KS;k++) wreg[k] = wl[c*KS+k];
  float bias = bl[c];
  for (int p = pb; p < 280; p += 8) {
    float acc = 0.f;
    if (p < 278) {
      acc = bias;
      #pragma unroll
      for (int k=0;k<KS;k++) acc = fmaf(wreg[k], xin[2*p+k], acc);
      acc = fmaxf(acc, 0.f);
    }
    g1p[((long)n*280 + p)*32 + c] = __float2bfloat16(acc);
  }
}

// ---------------- BN1 column sums ----------------
__global__ __launch_bounds__(256) void k_colsum2(const __hip_bfloat16* __restrict__ g1p,
    float* __restrict__ colS, float* __restrict__ colSQ) {
  int gid = blockIdx.x*256 + threadIdx.x;
  int cg = gid % 1120, chunk = gid / 1120;
  int col0 = cg*8;
  float s[8], sq[8];
  #pragma unroll
  for (int j=0;j<8;j++) { s[j]=0.f; sq[j]=0.f; }
  int n0 = chunk*128;
  const short* gp = (const short*)g1p;
  for (int n=n0; n<n0+128; n++) {
    s8v v = *(const s8v*)(gp + (long)n*8960 + col0);
    #pragma unroll
    for (int j=0;j<8;j++) { float f = cvt_bf(v[j]); s[j]+=f; sq[j]+=f*f; }
  }
  #pragma unroll
  for (int j=0;j<8;j++) { atomicAdd(&colS[col0+j], s[j]); atomicAdd(&colSQ[col0+j], sq[j]); }
}

__global__ __launch_bounds__(64) void k_bn1aff(const float* __restrict__ colS,
    const float* __restrict__ colSQ, const float* __restrict__ g, const float* __restrict__ b,
    float* __restrict__ a1, float* __restrict__ d1) {
  int i = blockIdx.x*64 + threadIdx.x;
  if (i >= NT*NC1) return;
  int t = i / NC1, c = i % NC1;
  float s=0.f, sq=0.f;
  for (int p=6*t; p<6*t+140; p++) { s += colS[p*32+c]; sq += colSQ[p*32+c]; }
  float cnt = 4096.f*140.f;
  float m = s/cnt;
  float v = sq/cnt - m*m;
  float a = g[c]*rsqrtf(v+EPS);
  a1[i] = a;
  d1[i] = b[c] - m*a;
}

// ---------------- fold BN1 into conv2 weights ----------------
__global__ __launch_bounds__(256) void k_w2b(const float* __restrict__ w2,
    const float* __restrict__ b2, const float* __restrict__ a1, const float* __restrict__ d1,
    __hip_bfloat16* __restrict__ w2b, float* __restrict__ cb2) {
  int i = blockIdx.x*256 + threadIdx.x;
  if (i >= NT*NC2) return;
  int t = i>>6, c2 = i&63;
  float cb = b2[c2];
  for (int c1=0;c1<NC1;c1++) {
    float a = a1[t*32+c1], d = d1[t*32+c1];
    float wsum = 0.f;
    for (int k=0;k<KS;k++) {
      float wv = w2[(c2*32+c1)*KS+k];
      wsum += wv;
      w2b[(((long)t*10 + k)*64 + c2)*32 + c1] = __float2bfloat16(wv*a);
    }
    cb += wsum*d;
  }
  cb2[i] = cb;
}

// ---------------- conv2 as 10 accumulated MFMAs ------
__global__ __launch_bounds__(256) void k_conv2m(const __hip_bfloat16* __restrict__ g1p,
    const __hip_bfloat16* __restrict__ w2b, const float* __restrict__ cb2,
    __hip_bfloat16* __restrict__ y2, float* __restrict__ stats, int t) {
  __shared__ __attribute__((aligned(16))) short patch[4*140*40];
  __shared__ float sS[64], sQ[64];
  int tid = threadIdx.x, w = tid>>6, lane = tid&63;
  int n0 = blockIdx.x*4;
  if (tid < 64) { sS[tid]=0.f; sQ[tid]=0.f; }
  const short* gp = (const short*)g1p;
  for (int f = tid; f < 2240; f += 256) {
    int nn = f / 560, rr = f % 560;
    int row = rr >> 2, kq = rr & 3;
    s8v v = *(const s8v*)(gp + ((long)(n0+nn)*280 + 6*t + row)*32 + kq*8);
    *(s8v*)&patch[(nn*140 + row)*40 + kq*8] = v;
  }
  __syncthreads();
  int q = lane>>4, m = lane&15;
  f4v acc[5][4];
  #pragma unroll
  for (int a=0;a<5;a++)
    #pragma unroll
    for (int b=0;b<4;b++) acc[a][b] = (f4v){0.f,0.f,0.f,0.f};
  const short* wb = (const short*)w2b + (long)t*10*64*32;
  for (int s=0; s<10; s++) {
    int j = s>>1, r = s&1;
    s8v bfr[4];
    #pragma unroll
    for (int ng=0; ng<4; ng++)
      bfr[ng] = *(const s8v*)(wb + (long)(s*64 + ng*16 + m)*32 + q*8);
    #pragma unroll
    for (int mg=0; mg<5; mg++) {
      int l2 = mg*16 + m;
      int u = l2 + j; u = (u>69)?69:u;
      s8v afr = *(const s8v*)&patch[(w*140 + 2*u + r)*40 + q*8];
      #pragma unroll
      for (int ng=0; ng<4; ng++)
        acc[mg][ng] = __builtin_amdgcn_mfma_f32_16x16x32_bf16(afr, bfr[ng], acc[mg][ng], 0,0,0);
    }
  }
  int node = n0 + w;
  float s1a[4]={0,0,0,0}, s2a[4]={0,0,0,0};
  #pragma unroll
  for (int mg=0; mg<5; mg++) {
    int l2b = mg*16 + q*4;
    #pragma unroll
    for (int ng=0; ng<4; ng++) {
      int c2 = ng*16 + m;
      float cbv = cb2[t*64 + c2];
      float vv[4];
      #pragma unroll
      for (int rr=0; rr<4; rr++) {
        float v = fmaxf(acc[mg][ng][rr] + cbv, 0.f);
        vv[rr] = v;
        if (l2b + rr < 66) { s1a[ng] += v; s2a[ng] += v*v; }
      }
      long base = ((long)node*64 + c2)*68 + l2b;
      if (mg < 4) {
        s4v o;
        #pragma unroll
        for (int rr=0; rr<4; rr++) o[rr] = bf16bits(vv[rr]);
        *(s4v*)((short*)y2 + base) = o;
      } else {
        for (int rr=0; rr<4; rr++) if (l2b+rr < 66) y2[base+rr] = __float2bfloat16(vv[rr]);
      }
    }
  }
  #pragma unroll
  for (int ng=0; ng<4; ng++) {
    atomicAdd(&sS[ng*16+m], s1a[ng]);
    atomicAdd(&sQ[ng*16+m], s2a[ng]);
  }
  __syncthreads();
  if (tid < 64) {
    atomicAdd(&stats[t*128+tid], sS[tid]);
    atomicAdd(&stats[t*128+64+tid], sQ[tid]);
  }
}

// ---------------- BN2 + fcconv + relu + fc ----------------
__global__ __launch_bounds__(256) void k_pass2(const __hip_bfloat16* __restrict__ y2,
    const float* __restrict__ stats, const float* __restrict__ bn2g, const float* __restrict__ bn2b,
    const float* __restrict__ fcvw, const float* __restrict__ fcvb,
    const float* __restrict__ fcW, const float* __restrict__ fcB,
    float* __restrict__ embs, int t) {
  __shared__ __attribute__((aligned(16))) short yb[4*64*68];
  __shared__ float fw[66*64];
  __shared__ float fwa[64], cfcs[64];
  __shared__ float zbuf[4][68];
  int tid = threadIdx.x;
  int n0 = blockIdx.x*4;
  const short* yg = (const short*)y2;
  for (int f=tid; f<2176; f+=256)
    *(s8v*)&yb[f*8] = *(const s8v*)(yg + (long)n0*64*68 + f*8);
  for (int i=tid; i<66*64; i+=256) fw[i] = fcW[i];
  if (tid < 64) {
    float cnt = 4096.f*66.f;
    float m = stats[t*128+tid]/cnt;
    float v = stats[t*128+64+tid]/cnt - m*m;
    float a = bn2g[tid]*rsqrtf(v+EPS);
    float d = bn2b[tid] - m*a;
    fwa[tid]  = fcvw[tid]*a;
    cfcs[tid] = fcvw[tid]*d;
  }
  __syncthreads();
  float cfc = fcvb[0];
  #pragma unroll 8
  for (int c=0;c<64;c++) cfc += cfcs[c];
  for (int idx=tid; idx<4*66; idx+=256) {
    int nn = idx/66, l = idx%66;
    float z = cfc;
    #pragma unroll 8
    for (int c=0;c<64;c++) z = fmaf(fwa[c], cvt_bf(yb[(nn*64+c)*68 + l]), z);
    zbuf[nn][l] = fmaxf(z, 0.f);
  }
  __syncthreads();
  int nn = tid>>6, e = tid&63;
  float acc = fcB[e];
  for (int l=0;l<66;l++) acc = fmaf(zbuf[nn][l], fw[l*64+e], acc);
  embs[((long)t*NN + n0+nn)*64 + e] = acc;
}

// ---------------- adj fp32 -> bf16 ----------------
__global__ __launch_bounds__(256) void k_cvtadj(const float* __restrict__ adj,
    __hip_bfloat16* __restrict__ adjb) {
  long gid = ((long)blockIdx.x*256 + threadIdx.x)*4;
  float4 v = *(const float4*)(adj + gid);
  adjb[gid+0] = __float2bfloat16(v.x);
  adjb[gid+1] = __float2bfloat16(v.y);
  adjb[gid+2] = __float2bfloat16(v.z);
  adjb[gid+3] = __float2bfloat16(v.w);
}

// ---------------- bf16 MFMA GEMM: P = A @ Bt^T ----------
// BM=64, 2-deep register prefetch, __syncthreads barriers (round-9 best config).
// zsplit>1: store partials only; k_redT reduces (kernel-boundary sync).
// zsplit==1: direct fused epilogue (mode, fp32 dst, optional bf16T) from acc.
template<int BN>
__global__ __launch_bounds__(256) void k_mmb(const __hip_bfloat16* __restrict__ A,
    const __hip_bfloat16* __restrict__ Bt, float* __restrict__ P,
    int N, int kchunk, long zoff,
    float* __restrict__ dst, const float* __restrict__ ref,
    __hip_bfloat16* __restrict__ dstT, int mode, int writeT, int zsplit) {
  constexpr int BM = 64;
  constexpr int WN = BN/2;
  constexpr int MI = 2;
  constexpr int NJ = WN/16;
  constexpr int AIT = 2;
  constexpr int BIT = BN*8/256;
  __shared__ __attribute__((aligned(16))) short As[BM*64];
  __shared__ __attribute__((aligned(16))) short Bs[BN*64];
  int tid = threadIdx.x;
  int w = tid >> 6, lane = tid & 63;
  int wm = w >> 1, wn = w & 1;
  int q = lane >> 4, m = lane & 15;
  long Mb = (long)blockIdx.x * BM;
  int Nb = blockIdx.y * BN;
  int k0 = blockIdx.z * kchunk;
  const short* Ag = (const short*)A;
  const short* Bg = (const short*)Bt;
  s8v arA[AIT], brA[BIT], arB[AIT], brB[BIT];

  auto loadAr = [&](s8v* d, int kb){
    #pragma unroll
    for (int i2=0;i2<AIT;i2++){ int f=tid+i2*256; int kq=f&7, row=f>>3;
      d[i2] = *(const s8v*)(Ag + (Mb+row)*4096 + kb + kq*8); } };
  auto loadBr = [&](s8v* d, int kb){
    #pragma unroll
    for (int i2=0;i2<BIT;i2++){ int f=tid+i2*256; int kq=f&7, col=f>>3;
      d[i2] = *(const s8v*)(Bg + (long)(Nb+col)*4096 + kb + kq*8); } };

  f4v acc[MI][NJ];
  #pragma unroll
  for (int i=0;i<MI;i++)
    #pragma unroll
    for (int j=0;j<NJ;j++) acc[i][j] = (f4v){0.f,0.f,0.f,0.f};

  auto writeS = [&](s8v* a, s8v* b){
    #pragma unroll
    for (int i2=0;i2<AIT;i2++){ int f=tid+i2*256; int kq=f&7, row=f>>3;
      *(s8v*)&As[(row*8 + (kq ^ (row&7)))*8] = a[i2]; }
    #pragma unroll
    for (int i2=0;i2<BIT;i2++){ int f=tid+i2*256; int kq=f&7, col=f>>3;
      *(s8v*)&Bs[(col*8 + (kq ^ (col&7)))*8] = b[i2]; } };
  auto compute = [&](){
    #pragma unroll
    for (int h2=0; h2<2; ++h2) {
      s8v af[MI], bfv[NJ];
      #pragma unroll
      for (int i=0;i<MI;i++) {
        int row = wm*32 + i*16 + m;
        af[i] = *(const s8v*)&As[(row*8 + ((h2*4+q) ^ (row&7)))*8];
      }
      #pragma unroll
      for (int j=0;j<NJ;j++) {
        int col = wn*WN + j*16 + m;
        bfv[j] = *(const s8v*)&Bs[(col*8 + ((h2*4+q) ^ (col&7)))*8];
      }
      #pragma unroll
      for (int i=0;i<MI;i++)
        #pragma unroll
        for (int j=0;j<NJ;j++)
          acc[i][j] = __builtin_amdgcn_mfma_f32_16x16x32_bf16(af[i], bfv[j], acc[i][j], 0, 0, 0);
    } };

  loadAr(arA, k0);      loadBr(brA, k0);
  loadAr(arB, k0+64);   loadBr(brB, k0+64);
  int kiters = kchunk >> 6;   // always even here
  for (int it = 0; it < kiters; it += 2) {
    __syncthreads();
    writeS(arA, brA);
    __syncthreads();
    { int kn = (it+2 < kiters) ? k0 + (it+2)*64 : k0;
      loadAr(arA, kn); loadBr(brA, kn); }
    compute();
    __syncthreads();
    writeS(arB, brB);
    __syncthreads();
    { int kn = (it+3 < kiters) ? k0 + (it+3)*64 : k0;
      loadAr(arB, kn); loadBr(brB, kn); }
    compute();
  }

  if (zsplit > 1) {
    float* pp = P + (long)blockIdx.z * zoff;
    #pragma unroll
    for (int i=0;i<MI;i++) {
      long row0 = Mb + wm*32 + i*16 + q*4;
      #pragma unroll
      for (int j=0;j<NJ;j++) {
        int col = Nb + wn*WN + j*16 + m;
        #pragma unroll
        for (int r=0;r<4;r++) pp[(row0+r)*N + col] = acc[i][j][r];
      }
    }
  } else {
    #pragma unroll
    for (int i=0;i<MI;i++) {
      long row0 = Mb + wm*32 + i*16 + q*4;
      #pragma unroll
      for (int j=0;j<NJ;j++) {
        int col = Nb + wn*WN + j*16 + m;
        float vr[4];
        #pragma unroll
        for (int r=0;r<4;r++) {
          long idx = (row0+r)*N + col;
          float v = acc[i][j][r];
          if (mode) v = 2.f*v - ref[idx];
          dst[idx] = v;
          vr[r] = v;
        }
        if (writeT) {
          s4v o;
          #pragma unroll
          for (int r=0;r<4;r++) o[r] = bf16bits(vr[r]);
          *(s4v*)((short*)dstT + (long)col*4096 + row0) = o;
        }
      }
    }
  }
}

// ---------------- split-K reduce + optional (2x-ref) + optional bf16T -------
__global__ __launch_bounds__(256) void k_redT(const float* __restrict__ P,
    float* __restrict__ dst, const float* __restrict__ ref,
    __hip_bfloat16* __restrict__ dstT, int ldc, int ksplit, long zoff, int mode,
    int writeF, int writeT) {
  __shared__ float tile[64][65];
  int tid = threadIdx.x;
  int n0 = blockIdx.x*64, c0 = blockIdx.y*64;
  for (int i=0; i<16; i++) {
    int flat = i*256 + tid;
    int cc = flat & 63, nn = flat >> 6;
    long idx = (long)(n0+nn)*ldc + c0+cc;
    float v = P[idx];
    for (int s=1; s<ksplit; s++) v += P[(long)s*zoff + idx];
    if (mode) v = 2.f*v - ref[idx];
    if (writeF) dst[idx] = v;
    tile[nn][cc] = v;
  }
  __syncthreads();
  if (writeT) {
    for (int i=0; i<16; i++) {
      int flat = i*256 + tid;
      int nn = flat & 63, cc = flat >> 6;
      dstT[(long)(c0+cc)*4096 + n0+nn] = __float2bfloat16(tile[nn][cc]);
    }
  }
}

// ---------------- prepX: all 12 X=[et|0] fp32 + Xt bf16 in one launch ------
__global__ __launch_bounds__(256) void k_prepX(const float* __restrict__ embs,
    float* __restrict__ X12, __hip_bfloat16* __restrict__ Xt12) {
  __shared__ float tile[64][65];
  int tid = threadIdx.x;
  int n0 = blockIdx.x*64, c0 = blockIdx.y*64, t = blockIdx.z;
  float* X = X12 + (long)t*524288;
  __hip_bfloat16* Xt = Xt12 + (long)t*524288;
  for (int i=0; i<16; i++) {
    int flat = i*256 + tid;
    int cc = flat & 63, nn = flat >> 6;
    int col = c0 + cc, n = n0 + nn;
    float v = (col < 64) ? embs[((long)t*NN + n)*64 + col] : 0.f;
    X[(long)n*128 + col] = v;
    tile[nn][cc] = v;
  }
  __syncthreads();
  for (int i=0; i<16; i++) {
    int flat = i*256 + tid;
    int nn = flat & 63, cc = flat >> 6;
    Xt[(long)(c0+cc)*4096 + n0+nn] = __float2bfloat16(tile[nn][cc]);
  }
}

// ---------------- Eb = [emb12..23 | h | 0pad] fp32 ld896 + Ebt bf16 ---------
__global__ __launch_bounds__(256) void k_gatherE(const float* __restrict__ embs,
    const float* __restrict__ h, float* __restrict__ Eb, __hip_bfloat16* __restrict__ Ebt) {
  __shared__ float tile[64][65];
  int tid = threadIdx.x;
  int n0 = blockIdx.x*64, c0 = blockIdx.y*64;
  for (int i=0; i<16; i++) {
    int flat = i*256 + tid;
    int cc = flat & 63, nn = flat >> 6;
    int col = c0 + cc, n = n0 + nn;
    float v;
    if (col < 768)      v = embs[((long)(12 + (col>>6))*NN + n)*64 + (col & 63)];
    else if (col < 832) v = h[(long)n*64 + (col - 768)];
    else                v = 0.f;
    Eb[(long)n*896 + col] = v;
    tile[nn][cc] = v;
  }
  __syncthreads();
  for (int i=0; i<16; i++) {
    int flat = i*256 + tid;
    int nn = flat & 63, cc = flat >> 6;
    Ebt[(long)(c0+cc)*4096 + n0+nn] = __float2bfloat16(tile[nn][cc]);
  }
}

// ---------------- gather-GEMM + fused DCGRU epilogue (fp32 FMA, encoder) ----
template<int RPT>
__global__ __launch_bounds__(256) void k_ggemm2(
    Src s0, Src s1, Src s2, Src s3, Src s4, Src s5,
    const float* __restrict__ W, const float* __restrict__ bias, int N, int mode,
    float* __restrict__ o1, int ld1, int t1, __hip_bfloat16* __restrict__ o1t,
    __hip_bfloat16* __restrict__ o2, const float* __restrict__ h,
    float* __restrict__ xnext, __hip_bfloat16* __restrict__ xtnext) {
  constexpr int BM = 16*RPT;
  __shared__ float Ags[32][BM+4];
  __shared__ float Bgs[32][68];
  int tid = threadIdx.x;
  long Mb = (long)blockIdx.x * BM;
  int Nb = blockIdx.y * 64;
  int tr = tid >> 4, tc = tid & 15;
  float acc[RPT][4];
  #pragma unroll
  for (int a=0;a<RPT;a++)
    #pragma unroll
    for (int b=0;b<4;b++) acc[a][b] = 0.f;
  float ar[2*RPT], br[8];
  auto pick = [&](int c)->Src {
    switch (c >> 1) {
      case 0: return s0; case 1: return s1; case 2: return s2;
      case 3: return s3; case 4: return s4; default: return s5;
    } };
  auto loadA = [&](int c){
    Src S = pick(c); int cc0 = (c & 1)*32;
    #pragma unroll
    for (int h0=0; h0<2*RPT; h0++) {
      int idx = tid + h0*256;
      int kk = idx & 31, mm = idx >> 5;
      long row = Mb + mm; int tt = (int)(row >> 12); int n = (int)(row & 4095);
      ar[h0] = S.p[(long)n*S.ld + S.off + S.tmul*(tt*64) + cc0 + kk];
    } };
  auto loadB = [&](int c){
    #pragma unroll
    for (int h0=0; h0<8; h0++) {
      int idx = tid + h0*256;
      int kk = idx >> 6, cc = idx & 63;
      br[h0] = W[(long)(c*32+kk)*N + Nb + cc];
    } };
  loadA(0); loadB(0);
  for (int c=0; c<12; c++) {
    __syncthreads();
    #pragma unroll
    for (int h0=0; h0<2*RPT; h0++) {
      int idx = tid + h0*256;
      int kk = idx & 31, mm = idx >> 5;
      Ags[kk][mm] = ar[h0];
    }
    #pragma unroll
    for (int h0=0; h0<8; h0++)     { int idx = tid + h0*256; Bgs[idx >> 6][idx & 63] = br[h0]; }
    __syncthreads();
    if (c < 11) { loadA(c+1); loadB(c+1); }
    #pragma unroll
    for (int kk=0; kk<32; kk++) {
      f4v b4 = *(const f4v*)&Bgs[kk][tc*4];
      if constexpr (RPT == 2) {
        f2v a0 = *(const f2v*)&Ags[kk][tr*2];
        #pragma unroll
        for (int rr=0; rr<2; rr++)
          #pragma unroll
          for (int j=0; j<4; j++)
            acc[rr][j] = fmaf(a0[rr], b4[j], acc[rr][j]);
      } else {
        float a0 = Ags[kk][tr];
        #pragma unroll
        for (int j=0; j<4; j++)
          acc[0][j] = fmaf(a0, b4[j], acc[0][j]);
      }
    }
  }
  #pragma unroll
  for (int rr=0; rr<RPT; rr++) {
    long row = Mb + tr*RPT + rr;
    int tt = (int)(row >> 12); int n = (int)(row & 4095);
    #pragma unroll
    for (int j=0; j<4; j++) {
      int col = Nb + tc*4 + j;
      float g = acc[rr][j] + bias[col];
      if (mode == 0) {
        float sg = 1.f/(1.f + expf(-g));
        if (col < 64) {
          float v = sg * h[(long)n*64 + col];
          o1[(long)n*ld1 + (long)t1*tt*64 + col] = v;
          o1t[((long)t1*tt*64 + col)*4096 + n] = __float2bfloat16(v);
        } else {
          o2[(long)row*64 + (col - 64)] = __float2bfloat16(sg);
        }
      } else {
        float uu = __bfloat162float(o2[(long)row*64 + col]);
        float v = uu*h[(long)n*64 + col] + (1.f - uu)*tanhf(g);
        o1[(long)row*64 + col] = v;
        if (xnext) {
          xnext[(long)n*128 + 64 + col] = v;
          xtnext[(long)(64 + col)*4096 + n] = __float2bfloat16(v);
        }
      }
    }
  }
}

// ---------------- MFMA gather-GEMM + fused DCGRU epilogue (decoder) ----
__global__ __launch_bounds__(256) void k_ggemm3(
    Src s0, Src s1, Src s2, Src s3, Src s4, Src s5,
    const float* __restrict__ W, const float* __restrict__ bias, int N, int mode,
    float* __restrict__ o1, int ld1, int t1, __hip_bfloat16* __restrict__ o1t,
    __hip_bfloat16* __restrict__ o2, const float* __restrict__ h) {
  __shared__ __attribute__((aligned(16))) short As[64*32];
  __shared__ __attribute__((aligned(16))) short Bs[64*32];
  int tid = threadIdx.x;
  int w = tid >> 6, lane = tid & 63;
  int wm = w >> 1, wn = w & 1;
  int q = lane >> 4, m = lane & 15;
  long Mb = (long)blockIdx.x * 64;
  int Nb = blockIdx.y * 64;
  int arow = tid >> 2, ag = tid & 3;
  int bnn  = tid & 63, bg = tid >> 6;
  auto pick = [&](int c)->Src {
    switch (c >> 1) {
      case 0: return s0; case 1: return s1; case 2: return s2;
      case 3: return s3; case 4: return s4; default: return s5;
    } };
  f4v a0r, a1r; float wr[8];
  auto loadA = [&](int c){
    Src S = pick(c); int cc0 = (c & 1)*32;
    long row = Mb + arow; int tt = (int)(row >> 12); int n = (int)(row & 4095);
    const float* p = S.p + (long)n*S.ld + S.off + S.tmul*(tt*64) + cc0 + ag*8;
    a0r = *(const f4v*)p; a1r = *(const f4v*)(p+4);
  };
  auto loadB = [&](int c){
    #pragma unroll
    for (int jj=0;jj<8;jj++) wr[jj] = W[(long)(c*32 + bg*8 + jj)*N + Nb + bnn];
  };
  f4v acc[2][2];
  #pragma unroll
  for (int i=0;i<2;i++)
    #pragma unroll
    for (int j=0;j<2;j++) acc[i][j] = (f4v){0.f,0.f,0.f,0.f};
  loadA(0); loadB(0);
  for (int c=0; c<12; c++) {
    __syncthreads();
    {
      s8v va;
      #pragma unroll
      for (int jj=0;jj<4;jj++) { va[jj] = bf16bits(a0r[jj]); va[4+jj] = bf16bits(a1r[jj]); }
      *(s8v*)&As[(arow*4 + (ag ^ (arow&3)))*8] = va;
      s8v vb;
      #pragma unroll
      for (int jj=0;jj<8;jj++) vb[jj] = bf16bits(wr[jj]);
      *(s8v*)&Bs[(bnn*4 + (bg ^ (bnn&3)))*8] = vb;
    }
    __syncthreads();
    if (c < 11) { loadA(c+1); loadB(c+1); }
    s8v af[2], bfv[2];
    #pragma unroll
    for (int i=0;i<2;i++) {
      int row = wm*32 + i*16 + m;
      af[i] = *(const s8v*)&As[(row*4 + (q ^ (row&3)))*8];
    }
    #pragma unroll
    for (int j=0;j<2;j++) {
      int col = wn*32 + j*16 + m;
      bfv[j] = *(const s8v*)&Bs[(col*4 + (q ^ (col&3)))*8];
    }
    #pragma unroll
    for (int i=0;i<2;i++)
      #pragma unroll
      for (int j=0;j<2;j++)
        acc[i][j] = __builtin_amdgcn_mfma_f32_16x16x32_bf16(af[i], bfv[j], acc[i][j], 0, 0, 0);
  }
  #pragma unroll
  for (int i=0;i<2;i++) {
    #pragma unroll
    for (int r=0;r<4;r++) {
      long row = Mb + wm*32 + i*16 + q*4 + r;
      int tt = (int)(row >> 12); int n = (int)(row & 4095);
      #pragma unroll
      for (int j=0;j<2;j++) {
        int col = Nb + wn*32 + j*16 + m;
        float g = acc[i][j][r] + bias[col];
        if (mode == 0) {
          float sg = 1.f/(1.f + expf(-g));
          if (col < 64) {
            float v = sg * h[(long)n*64 + col];
            o1[(long)n*ld1 + (long)t1*tt*64 + col] = v;
            o1t[((long)t1*tt*64 + col)*4096 + n] = __float2bfloat16(v);
          } else {
            o2[(long)row*64 + (col - 64)] = __float2bfloat16(sg);
          }
        } else {
          float uu = __bfloat162float(o2[(long)row*64 + col]);
          o1[(long)row*64 + col] = uu*h[(long)n*64 + col] + (1.f - uu)*tanhf(g);
        }
      }
    }
  }
}

// ---------------- preds ----------------
__global__ __launch_bounds__(256) void k_pred(const float* __restrict__ hd,
    const float* __restrict__ pw, const float* __restrict__ pb, float* __restrict__ out) {
  int gid = blockIdx.x*256 + threadIdx.x;
  int wid = gid >> 6;
  int lane = threadIdx.x & 63;
  if (wid >= 12*NN) return;
  int t = wid >> 12, n = wid & 4095;
  float hv = hd[(long)wid*64 + lane];
  float res = 0.f;
  #pragma unroll
  for (int p=0;p<12;p++) {
    float v = hv * pw[lane*12 + p];
    #pragma unroll
    for (int off=32; off>0; off>>=1) v += __shfl_xor(v, off, 64);
    if (lane == p) res = v + pb[p];
  }
  if (lane < 12) out[(long)n*144 + t*12 + lane] = res;
}

// ============================================================================
extern "C" void kernel_launch(void* const* d_in, const int* in_sizes, int n_in,
                              void* d_out, int out_size, void* d_ws, size_t ws_size,
                              hipStream_t stream) {
  const float* inp  = (const float*)d_in[0];
  const float* c1w  = (const float*)d_in[2];
  const float* c1b  = (const float*)d_in[3];
  const float* c2w  = (const float*)d_in[4];
  const float* c2b  = (const float*)d_in[5];
  const float* bn1g = (const float*)d_in[6];
  const float* bn1b = (const float*)d_in[7];
  const float* bn2g = (const float*)d_in[8];
  const float* bn2b = (const float*)d_in[9];
  const float* fcvw = (const float*)d_in[10];
  const float* fcvb = (const float*)d_in[11];
  const float* fcW  = (const float*)d_in[12];
  const float* fcB  = (const float*)d_in[13];
  const float* eWg  = (const float*)d_in[14];
  const float* ebg  = (const float*)d_in[15];
  const float* eWc  = (const float*)d_in[16];
  const float* ebc  = (const float*)d_in[17];
  const float* dWg  = (const float*)d_in[18];
  const float* dbg  = (const float*)d_in[19];
  const float* dWc  = (const float*)d_in[20];
  const float* dbc  = (const float*)d_in[21];
  const float* pw   = (const float*)d_in[22];
  const float* pb   = (const float*)d_in[23];
  const float* adj  = (const float*)d_in[n_in-1];
  for (int i=0;i<n_in;i++) if (in_sizes[i] == NN*NN) adj = (const float*)d_in[i];

  float* ws = (float*)d_ws;
  float* colS  = ws + O_COLS;
  float* colSQ = ws + O_COLSQ;
  float* stats = ws + O_STATS;
  float* h     = ws + O_H;
  float* a1    = ws + O_A1;
  float* d1    = ws + O_D1;
  float* cb2   = ws + O_CB2;
  __hip_bfloat16* w2b = (__hip_bfloat16*)(ws + O_W2B);
  __hip_bfloat16* g1p = (__hip_bfloat16*)(ws + O_G1P);
  __hip_bfloat16* y2  = (__hip_bfloat16*)(ws + O_Y2);
  float* embs  = ws + O_EMBS;
  __hip_bfloat16* adjb = (__hip_bfloat16*)(ws + O_ADJB);
  float* Pp    = ws + O_PP;
  float* T1    = ws + O_T1;
  __hip_bfloat16* T1t = (__hip_bfloat16*)(ws + O_T1T);
  float* T2    = ws + O_T2;
  float* rh    = ws + O_RH;
  __hip_bfloat16* rht = (__hip_bfloat16*)(ws + O_RHT);
  float* P1s   = ws + O_P1S;
  __hip_bfloat16* P1st = (__hip_bfloat16*)(ws + O_P1ST);
  float* P2s   = ws + O_P2S;
  __hip_bfloat16* ue  = (__hip_bfloat16*)(ws + O_UE);
  float* X12   = ws + O_X12;
  __hip_bfloat16* Xt12 = (__hip_bfloat16*)(ws + O_XT12);
  float* Eb    = ws + O_EB;
  __hip_bfloat16* Ebt = (__hip_bfloat16*)(ws + O_EBT);
  float* AE1   = ws + O_AE1;
  __hip_bfloat16* AE1t = (__hip_bfloat16*)(ws + O_AE1T);
  float* AE2   = ws + O_AE2;
  float* RHb   = ws + O_RHB;
  float* P1B   = ws + O_P1B;
  float* P2B   = ws + O_P2B;
  float* hd    = ws + O_HD;
  __hip_bfloat16* RHbt = Ebt;                              // Ebt dead by then
  __hip_bfloat16* P1Bt = (__hip_bfloat16*)(ws + O_P1BT);   // distinct from RHbt
  __hip_bfloat16* ud   = AE1t;

  auto S = [](const float* p, int ld, int off, int tmul){ Src s; s.p=p; s.ld=ld; s.off=off; s.tmul=tmul; return s; };

  hipMemsetAsync(ws, 0, ZERO_FLOATS*sizeof(float), stream);

  // ---- embedding (round-9 y2 path, best measured) ----
  k_conv1n<<<4096, 256, 0, stream>>>(inp, c1w, c1b, g1p);
  k_colsum2<<<140, 256, 0, stream>>>(g1p, colS, colSQ);
  k_bn1aff<<<12, 64, 0, stream>>>(colS, colSQ, bn1g, bn1b, a1, d1);
  k_w2b   <<<6, 256, 0, stream>>>(c2w, c2b, a1, d1, w2b, cb2);
  for (int t=0; t<NT; t++) {
    k_conv2m<<<1024, 256, 0, stream>>>(g1p, w2b, cb2, y2, stats, t);
    k_pass2 <<<1024, 256, 0, stream>>>(y2, stats, bn2g, bn2b, fcvw, fcvb, fcW, fcB, embs, t);
  }

  // ---- adj -> bf16 (w2b/g1p dead now) ----
  k_cvtadj<<<16384, 256, 0, stream>>>(adj, adjb);

  // ---- encoder (round 9 + N=128 GEMMs N-split BN=64, z=8 kept) ----
  k_prepX<<<dim3(64,2,12), 256, 0, stream>>>(embs, X12, Xt12);
  for (int t=0; t<12; t++) {
    const float* et = embs + (long)t*NN*64;
    float* X_t = X12 + (long)t*524288;
    __hip_bfloat16* Xt_t = Xt12 + (long)t*524288;
    float* Xn  = (t < 11) ? X12 + (long)(t+1)*524288 : (float*)nullptr;
    __hip_bfloat16* Xtn = (t < 11) ? Xt12 + (long)(t+1)*524288 : (__hip_bfloat16*)nullptr;
    k_mmb<64><<<dim3(64,2,8), 256, 0, stream>>>(adjb, Xt_t, Pp, 128, 512, 4096L*128,
        (float*)nullptr, (const float*)nullptr, (__hip_bfloat16*)nullptr, 0, 0, 8);
    k_redT<<<dim3(64,2), 256, 0, stream>>>(Pp, T1, (const float*)nullptr, T1t,
        128, 8, 4096L*128, 0, 1, 1);
    k_mmb<64><<<dim3(64,2,8), 256, 0, stream>>>(adjb, T1t, Pp, 128, 512, 4096L*128,
        (float*)nullptr, (const float*)nullptr, (__hip_bfloat16*)nullptr, 0, 0, 8);
    k_redT<<<dim3(64,2), 256, 0, stream>>>(Pp, T2, X_t, (__hip_bfloat16*)nullptr,
        128, 8, 4096L*128, 1, 1, 0);
    k_ggemm2<2><<<dim3(128,2), 256, 0, stream>>>(
        S(X_t,128,0,0), S(X_t,128,64,0), S(T1,128,0,0), S(T1,128,64,0), S(T2,128,0,0), S(T2,128,64,0),
        eWg, ebg, 128, 0, rh, 64, 0, rht, ue, h, (float*)nullptr, (__hip_bfloat16*)nullptr);
    k_mmb<64><<<dim3(64,1,8), 256, 0, stream>>>(adjb, rht, Pp, 64, 512, 4096L*64,
        (float*)nullptr, (const float*)nullptr, (__hip_bfloat16*)nullptr, 0, 0, 8);
    k_redT<<<dim3(64,1), 256, 0, stream>>>(Pp, P1s, (const float*)nullptr, P1st,
        64, 8, 4096L*64, 0, 1, 1);
    k_mmb<64><<<dim3(64,1,8), 256, 0, stream>>>(adjb, P1st, Pp, 64, 512, 4096L*64,
        (float*)nullptr, (const float*)nullptr, (__hip_bfloat16*)nullptr, 0, 0, 8);
    k_redT<<<dim3(64,1), 256, 0, stream>>>(Pp, P2s, rh, (__hip_bfloat16*)nullptr,
        64, 8, 4096L*64, 1, 1, 0);
    k_ggemm2<1><<<dim3(256,1), 256, 0, stream>>>(
        S(et,64,0,0), S(rh,64,0,0), S(T1,128,0,0), S(P1s,64,0,0), S(T2,128,0,0), S(P2s,64,0,0),
        eWc, ebc, 64, 1, h, 0, 0, (__hip_bfloat16*)nullptr, ue, h, Xn, Xtn);
  }

  // ---- decoder (round 9 verbatim: z=1 mmb<128> + MFMA ggemm3) ----
  k_gatherE<<<dim3(64,14), 256, 0, stream>>>(embs, h, Eb, Ebt);
  k_mmb<128><<<dim3(64,7,1), 256, 0, stream>>>(adjb, Ebt, Pp, 896, 4096, 0,
      AE1, (const float*)nullptr, AE1t, 0, 1, 1);
  k_mmb<128><<<dim3(64,7,1), 256, 0, stream>>>(adjb, AE1t, Pp, 896, 4096, 0,
      AE2, Eb, (__hip_bfloat16*)nullptr, 1, 0, 1);
  k_ggemm3<<<dim3(768,2), 256, 0, stream>>>(
      S(Eb,896,0,1), S(Eb,896,768,0), S(AE1,896,0,1), S(AE1,896,768,0), S(AE2,896,0,1), S(AE2,896,768,0),
      dWg, dbg, 128, 0, RHb, 768, 1, RHbt, ud, h);
  k_mmb<128><<<dim3(64,6,1), 256, 0, stream>>>(adjb, RHbt, Pp, 768, 4096, 0,
      P1B, (const float*)nullptr, P1Bt, 0, 1, 1);
  k_mmb<128><<<dim3(64,6,1), 256, 0, stream>>>(adjb, P1Bt, Pp, 768, 4096, 0,
      P2B, RHb, (__hip_bfloat16*)nullptr, 1, 0, 1);
  k_ggemm3<<<dim3(768,1), 256, 0, stream>>>(
      S(Eb,896,0,1), S(RHb,768,0,1), S(AE1,896,0,1), S(P1B,768,0,1), S(AE2,896,0,1), S(P2B,768,0,1),
      dWc, dbc, 64, 1, hd, 0, 0, (__hip_bfloat16*)nullptr, ud, h);

  k_pred<<<12288, 256, 0, stream>>>(hd, pw, pb, (float*)d_out);
}